// Round 1
// baseline (537.815 us; speedup 1.0000x reference)
//
#include <hip/hip_runtime.h>
#include <stdint.h>

constexpr int N_VOX = 200000;
constexpr int CIN   = 128;
constexpr int DM    = 128;
constexpr int NXC   = 400;
constexpr int NXY   = 160000;   // 400*400
constexpr int NPIX  = 640000;   // 4*160000
constexpr int PIXB  = 256;      // pixels per block
constexpr int CHUNK = 16;       // voxels per wave-chunk (one MFMA M-tile)

typedef __attribute__((ext_vector_type(8))) short short8v;
typedef __attribute__((ext_vector_type(4))) float f32x4;

__device__ __forceinline__ uint32_t pack_bf16_pair(float lo, float hi) {
  // RNE float->bf16, pack two into one u32 (lo = even index, hi = odd index)
  uint32_t ul = __float_as_uint(lo);
  uint32_t uh = __float_as_uint(hi);
  ul += 0x7fffu + ((ul >> 16) & 1u);
  uh += 0x7fffu + ((uh >> 16) & 1u);
  return (ul >> 16) | (uh & 0xffff0000u);
}

__global__ void init_inv_k(int* __restrict__ inv) {
  int i = blockIdx.x * 256 + threadIdx.x;
  if (i < NPIX) inv[i] = -1;
}

__global__ void scatter_inv_k(const int* __restrict__ coors, int* __restrict__ inv) {
  int v = blockIdx.x * 256 + threadIdx.x;
  if (v < N_VOX) {
    int b = coors[4 * v + 0];
    int y = coors[4 * v + 2];
    int x = coors[4 * v + 3];
    inv[b * NXY + y * NXC + x] = v;
  }
}

// One block = 256 contiguous pixels of one batch image (160000 % 256 == 0).
// LDS: W0 as bf16-pair words, row-major [c][64 words], XOR-swizzled (32 KiB)
//      per-wave x-chunk [16 rows][64 words], same swizzle (16 KiB)
__launch_bounds__(256, 3)
__global__ void fused_k(const float* __restrict__ xin,
                        const float* __restrict__ W0,
                        const float* __restrict__ b0,
                        const int* __restrict__ inv,
                        float* __restrict__ out) {
  __shared__ __align__(16) uint32_t w0k[DM * 64];
  __shared__ __align__(16) uint32_t xs[4][CHUNK * 64];
  __shared__ int list_pix[PIXB];
  __shared__ int list_vox[PIXB];
  __shared__ int cnt;

  const int tid  = threadIdx.x;
  const int lane = tid & 63;
  const int wv   = tid >> 6;

  // ---- stage W0 [c][k] f32 -> bf16-pair words, swizzled ----
  // word i = c*64 + w holds bf16(W0[c][2w]), bf16(W0[c][2w+1])
  // physical index: c*64 + (w ^ ((c&15)<<2))  (XOR on word-group bits only)
  #pragma unroll
  for (int it = 0; it < 32; ++it) {
    int i = tid + it * 256;
    int c = i >> 6;
    int w = i & 63;
    float2 f = *(const float2*)(W0 + c * CIN + w * 2);
    w0k[c * 64 + (w ^ ((c & 15) << 2))] = pack_bf16_pair(f.x, f.y);
  }
  if (tid == 0) cnt = 0;
  __syncthreads();

  const int pix0 = blockIdx.x * PIXB;
  const int bb   = pix0 / NXY;
  const int yx0  = pix0 - bb * NXY;
  float* const outb = out + (size_t)bb * DM * NXY + yx0;

  // ---- compact voxel pixels; zero-fill empty pixels (disjoint addresses) ----
  const int myinv = inv[pix0 + tid];
  if (myinv >= 0) {
    int pos = atomicAdd(&cnt, 1);
    list_pix[pos] = tid;
    list_vox[pos] = myinv;
  } else {
    #pragma unroll 4
    for (int c = 0; c < DM; ++c) outb[(size_t)c * NXY + tid] = 0.0f;
  }
  __syncthreads();
  const int ccnt = cnt;

  float bias[8];
  #pragma unroll
  for (int ct = 0; ct < 8; ++ct) bias[ct] = b0[ct * 16 + (lane & 15)];

  for (int base = wv * CHUNK; base < ccnt; base += 4 * CHUNK) {
    asm volatile("" ::: "memory");  // keep prev-iter LDS reads before new writes
    // ---- gather 16 x rows -> bf16 pairs -> swizzled per-wave LDS ----
    {
      const int j = lane >> 2;        // row 0..15
      const int q = lane & 3;         // k-quarter (32 floats)
      const int idx = base + j;
      const int vox = (idx < ccnt) ? list_vox[idx] : 0;
      const float* xr = xin + (size_t)vox * CIN + q * 32;
      uint32_t* xrow = &xs[wv][j * 64];
      #pragma unroll
      for (int t4 = 0; t4 < 4; ++t4) {
        float4 a = *(const float4*)(xr + t4 * 8);
        float4 b = *(const float4*)(xr + t4 * 8 + 4);
        uint4 wd;
        wd.x = pack_bf16_pair(a.x, a.y);
        wd.y = pack_bf16_pair(a.z, a.w);
        wd.z = pack_bf16_pair(b.x, b.y);
        wd.w = pack_bf16_pair(b.z, b.w);
        int w = q * 16 + t4 * 4;
        *(uint4*)(xrow + (w ^ ((j & 15) << 2))) = wd;
      }
    }
    asm volatile("" ::: "memory");  // LDS writes before fragment reads (same wave: DS pipe is in-order)

    // ---- A fragments: lane holds x[row=lane&15][k=(lane>>4)*8 + i] per k-step ----
    short8v afr[4];
    {
      const int j = lane & 15;
      const uint32_t* xrow = &xs[wv][j * 64];
      #pragma unroll
      for (int s = 0; s < 4; ++s) {
        int w = s * 16 + ((lane >> 4) << 2);
        afr[s] = *(const short8v*)(xrow + (w ^ ((j & 15) << 2)));
      }
    }

    f32x4 acc[8];
    #pragma unroll
    for (int ct = 0; ct < 8; ++ct) {
      f32x4 z = {0.f, 0.f, 0.f, 0.f};
      acc[ct] = z;
    }

    // ---- 8 channel-tiles x 4 k-steps of mfma_f32_16x16x32_bf16 ----
    #pragma unroll
    for (int ct = 0; ct < 8; ++ct) {
      const int c = ct * 16 + (lane & 15);
      const uint32_t* brow = w0k + c * 64;
      #pragma unroll
      for (int s = 0; s < 4; ++s) {
        int w = s * 16 + ((lane >> 4) << 2);
        short8v bfr = *(const short8v*)(brow + (w ^ ((c & 15) << 2)));
        acc[ct] = __builtin_amdgcn_mfma_f32_16x16x32_bf16(afr[s], bfr, acc[ct], 0, 0, 0);
      }
    }

    // ---- store: C/D layout col=lane&15 (channel), row=(lane>>4)*4+reg (voxel) ----
    #pragma unroll
    for (int ct = 0; ct < 8; ++ct) {
      const int c = ct * 16 + (lane & 15);
      #pragma unroll
      for (int r = 0; r < 4; ++r) {
        const int j = ((lane >> 4) << 2) + r;
        if (base + j < ccnt) {
          const int lp = list_pix[base + j];
          outb[(size_t)c * NXY + lp] = acc[ct][r] + bias[ct];
        }
      }
    }
  }
}

extern "C" void kernel_launch(void* const* d_in, const int* in_sizes, int n_in,
                              void* d_out, int out_size, void* d_ws, size_t ws_size,
                              hipStream_t stream) {
  (void)in_sizes; (void)n_in; (void)out_size; (void)ws_size;
  const float* xin  = (const float*)d_in[0];
  const float* W0   = (const float*)d_in[1];
  const float* b0   = (const float*)d_in[2];
  const int*  coors = (const int*)d_in[3];
  float* out = (float*)d_out;
  int*   inv = (int*)d_ws;   // 640000 * 4 B = 2.56 MB

  init_inv_k<<<dim3((NPIX + 255) / 256), dim3(256), 0, stream>>>(inv);
  scatter_inv_k<<<dim3((N_VOX + 255) / 256), dim3(256), 0, stream>>>(coors, inv);
  fused_k<<<dim3(NPIX / PIXB), dim3(256), 0, stream>>>(xin, W0, b0, inv, out);
}

// Round 2
// 420.488 us; speedup vs baseline: 1.2790x; 1.2790x over previous
//
#include <hip/hip_runtime.h>
#include <stdint.h>

constexpr int N_VOX = 200000;
constexpr int CIN   = 128;
constexpr int DM    = 128;
constexpr int NXC   = 400;
constexpr int NXY   = 160000;   // 400*400
constexpr int NPIX  = 640000;   // 4*160000
constexpr int PIXB  = 128;      // pixels per block -> ccnt <= 128 guaranteed
constexpr int NBLK  = NPIX / PIXB;   // 5000
constexpr int CSTR  = 129;      // canvas stride in floats (pad: 129%32==1 -> scatter conflict-free)

typedef __attribute__((ext_vector_type(8))) short short8v;
typedef __attribute__((ext_vector_type(4))) float f32x4;
typedef __attribute__((ext_vector_type(4))) uint32_t u32x4;

__device__ __forceinline__ uint32_t pack_bf16_pair(float lo, float hi) {
  // RNE float->bf16, pack two into one u32 (lo = even element, hi = odd element)
  uint32_t ul = __float_as_uint(lo);
  uint32_t uh = __float_as_uint(hi);
  ul += 0x7fffu + ((ul >> 16) & 1u);
  uh += 0x7fffu + ((uh >> 16) & 1u);
  return (ul >> 16) | (uh & 0xffff0000u);
}

// ---- prep: W0 f32 [c][k] -> packed bf16-pair words, XOR-swizzled, in d_ws ----
// word i = c*64 + w holds bf16(W0[c][2w]), bf16(W0[c][2w+1]); stored at c*64 + (w ^ ((c&15)<<2))
__global__ void w0conv_k(const float* __restrict__ W0, uint32_t* __restrict__ w0pre) {
  int i = blockIdx.x * 256 + threadIdx.x;          // 8192 words total
  int c = i >> 6;
  int w = i & 63;
  float2 f = *(const float2*)(W0 + c * CIN + w * 2);
  w0pre[c * 64 + (w ^ ((c & 15) << 2))] = pack_bf16_pair(f.x, f.y);
}

__global__ void init_inv_k(int4* __restrict__ inv4) {
  int i = blockIdx.x * 256 + threadIdx.x;          // NPIX/4 = 160000 = 625*256
  inv4[i] = make_int4(-1, -1, -1, -1);
}

__global__ void scatter_inv_k(const int4* __restrict__ coors, int* __restrict__ inv) {
  int v = blockIdx.x * 256 + threadIdx.x;
  if (v < N_VOX) {
    int4 c = coors[v];                             // {b, z, y, x}
    inv[c.x * NXY + c.z * NXC + c.w] = v;
  }
}

// One block = 128 contiguous pixels of one batch image (160000 % 128 == 0).
// LDS: W0 bf16 swizzled (32 KB) + canvas [32ch][129] f32 (16.5 KB) + lists (~1 KB)
__launch_bounds__(256, 3)
__global__ void fused_k(const float* __restrict__ xin,
                        const uint32_t* __restrict__ w0pre,
                        const float* __restrict__ b0,
                        const int* __restrict__ inv,
                        float* __restrict__ out) {
  __shared__ __align__(16) uint32_t w0k[DM * 64];        // 32 KB
  __shared__ __align__(16) float canvas[32][CSTR];       // 16.5 KB
  __shared__ int list_vox[PIXB];
  __shared__ int pos_of_pix[PIXB];
  __shared__ int cnt;

  const int tid  = threadIdx.x;
  const int lane = tid & 63;
  const int wv   = tid >> 6;

  // ---- copy pre-swizzled W0 into LDS: 2048 uint4 / 256 thr = 8 each ----
  {
    const uint4* src = (const uint4*)w0pre;
    uint4* dst = (uint4*)w0k;
    #pragma unroll
    for (int it = 0; it < 8; ++it) dst[tid + it * 256] = src[tid + it * 256];
  }
  if (tid == 0) cnt = 0;
  __syncthreads();

  const int pix0 = blockIdx.x * PIXB;
  const int bb   = pix0 / NXY;
  const int yx0  = pix0 - bb * NXY;
  float* const outb = out + (size_t)bb * DM * NXY + yx0;

  // ---- compact occupied pixels; record per-pixel compact position (or -1) ----
  if (tid < PIXB) {
    int mi = inv[pix0 + tid];
    int p = -1;
    if (mi >= 0) {
      p = atomicAdd(&cnt, 1);
      list_vox[p] = mi;
    }
    pos_of_pix[tid] = p;
  }
  __syncthreads();
  const int ccnt = cnt;
  const int nmt  = (ccnt + 15) >> 4;    // M-tiles of 16 voxels, <= 8

  // ---- per-thread bias (channel = ct*16 + (lane&15)) ----
  float bias[8];
  #pragma unroll
  for (int ct = 0; ct < 8; ++ct) bias[ct] = b0[ct * 16 + (lane & 15)];

  // ---- cache pos map for the dense-write pass (depends only on tid&7) ----
  const int q = tid & 7;
  int pr[4][4];
  #pragma unroll
  for (int f = 0; f < 4; ++f)
    #pragma unroll
    for (int e = 0; e < 4; ++e)
      pr[f][e] = pos_of_pix[(f * 8 + q) * 4 + e];

  // ---- A fragments direct from global: wave wv owns M-tiles wv and wv+4 ----
  // lane holds x[row=lane&15][k=(lane>>4)*8 + i] per k-step s (k = s*32 + klocal)
  short8v afr[2][4];
  #pragma unroll
  for (int m = 0; m < 2; ++m) {
    const int mt = wv + m * 4;
    if (mt < nmt) {
      int idx = mt * 16 + (lane & 15);
      int vox = list_vox[idx < ccnt ? idx : 0];
      const float* xr = xin + (size_t)vox * CIN + ((lane >> 4) << 3);
      #pragma unroll
      for (int s = 0; s < 4; ++s) {
        float4 a = *(const float4*)(xr + s * 32);
        float4 b = *(const float4*)(xr + s * 32 + 4);
        union { short8v sv; u32x4 uv; } cv;
        cv.uv.x = pack_bf16_pair(a.x, a.y);
        cv.uv.y = pack_bf16_pair(a.z, a.w);
        cv.uv.z = pack_bf16_pair(b.x, b.y);
        cv.uv.w = pack_bf16_pair(b.z, b.w);
        afr[m][s] = cv.sv;
      }
    } else {
      #pragma unroll
      for (int s = 0; s < 4; ++s) {
        union { short8v sv; u32x4 uv; } cv;
        cv.uv.x = cv.uv.y = cv.uv.z = cv.uv.w = 0u;
        afr[m][s] = cv.sv;
      }
    }
  }

  // ---- 4 channel-groups of 32: compute -> canvas scatter -> dense write ----
  const int chl_out = tid >> 3;        // 0..31: this thread's output channel-in-group
  for (int g = 0; g < 4; ++g) {
    f32x4 acc[2][2];                   // [ct-in-group][mtile]
    #pragma unroll
    for (int ci = 0; ci < 2; ++ci)
      #pragma unroll
      for (int m = 0; m < 2; ++m) {
        f32x4 z = {0.f, 0.f, 0.f, 0.f};
        acc[ci][m] = z;
      }

    #pragma unroll
    for (int ci = 0; ci < 2; ++ci) {
      const int ct = g * 2 + ci;
      const int c  = ct * 16 + (lane & 15);
      const uint32_t* brow = w0k + c * 64;
      #pragma unroll
      for (int s = 0; s < 4; ++s) {
        int w = s * 16 + ((lane >> 4) << 2);
        short8v bfr = *(const short8v*)(brow + (w ^ ((c & 15) << 2)));
        if (wv < nmt)
          acc[ci][0] = __builtin_amdgcn_mfma_f32_16x16x32_bf16(afr[0][s], bfr, acc[ci][0], 0, 0, 0);
        if (wv + 4 < nmt)
          acc[ci][1] = __builtin_amdgcn_mfma_f32_16x16x32_bf16(afr[1][s], bfr, acc[ci][1], 0, 0, 0);
      }
    }

    // scatter: C/D layout col=lane&15 (channel), row=(lane>>4)*4+r (voxel pos)
    #pragma unroll
    for (int ci = 0; ci < 2; ++ci) {
      const int ct  = g * 2 + ci;
      const int chl = ci * 16 + (lane & 15);
      #pragma unroll
      for (int m = 0; m < 2; ++m) {
        const int mt = wv + m * 4;
        if (mt < nmt) {
          #pragma unroll
          for (int r = 0; r < 4; ++r) {
            int j = mt * 16 + ((lane >> 4) << 2) + r;
            canvas[chl][j] = acc[ci][m][r] + bias[ct];
          }
        }
      }
    }
    __syncthreads();

    // dense write: 32 ch x 128 px, each thread 4 float4 (full 64B lines, once)
    {
      float* orow = outb + (size_t)(g * 32 + chl_out) * NXY;
      #pragma unroll
      for (int f = 0; f < 4; ++f) {
        f32x4 v;
        #pragma unroll
        for (int e = 0; e < 4; ++e) {
          int p = pr[f][e];
          v[e] = (p >= 0) ? canvas[chl_out][p] : 0.0f;
        }
        *(f32x4*)(orow + (f * 8 + q) * 4) = v;
      }
    }
    __syncthreads();
  }
}

extern "C" void kernel_launch(void* const* d_in, const int* in_sizes, int n_in,
                              void* d_out, int out_size, void* d_ws, size_t ws_size,
                              hipStream_t stream) {
  (void)in_sizes; (void)n_in; (void)out_size; (void)ws_size;
  const float* xin  = (const float*)d_in[0];
  const float* W0   = (const float*)d_in[1];
  const float* b0   = (const float*)d_in[2];
  const int*  coors = (const int*)d_in[3];
  float* out = (float*)d_out;

  int*      inv   = (int*)d_ws;                                  // 2.56 MB
  uint32_t* w0pre = (uint32_t*)((char*)d_ws + (size_t)NPIX * 4); // 32 KB, 16B-aligned

  w0conv_k<<<dim3(32), dim3(256), 0, stream>>>(W0, w0pre);
  init_inv_k<<<dim3(NPIX / 4 / 256), dim3(256), 0, stream>>>((int4*)inv);
  scatter_inv_k<<<dim3((N_VOX + 255) / 256), dim3(256), 0, stream>>>((const int4*)coors, inv);
  fused_k<<<dim3(NBLK), dim3(256), 0, stream>>>(xin, w0pre, b0, inv, out);
}